// Round 12
// baseline (826.769 us; speedup 1.0000x reference)
//
#include <hip/hip_runtime.h>
#include <math.h>

// Problem constants (fixed by setup_inputs)
#define B_    4
#define D_    96
#define H_    160
#define W_    160
#define HW_   (H_ * W_)
#define NVOX  (D_ * H_ * W_)
#define NBINS 50
#define NQ    78        // 5 moments + 8 gab + 6 lbp + 9 glcm + 50 hist
#define CZ    8
#define NCHUNK (D_ / CZ)          // 12
#define NTILE 50                  // x-y tiles (32x16 over 160x160)
#define NSLOTS (NTILE * NCHUNK)   // 600 partial slots per batch
#define LASTP ((D_ - 1) * HW_)

typedef float f2 __attribute__((ext_vector_type(2)));

// readfirstlane a float into an SGPR-resident uniform value
__device__ __forceinline__ float rfl(float v) {
    return __uint_as_float(__builtin_amdgcn_readfirstlane(__float_as_uint(v)));
}

// load raw 3x4 window rows of plane at element offset zo into slot s
#define LOADP(s, zo) do {                                                   \
    _Pragma("unroll")                                                       \
    for (int r_ = 0; r_ < 3; ++r_) {                                        \
        Xw[s][r_][0] = xbb[(zo) + rowoff[r_] + xL];                         \
        f2 t_ = *(const f2*)(xbb + (zo) + rowoff[r_] + gx);                 \
        Xw[s][r_][1] = t_.x; Xw[s][r_][2] = t_.y;                           \
        Xw[s][r_][3] = xbb[(zo) + rowoff[r_] + xR];                         \
    }                                                                       \
} while (0)

// boundary zeroing (rows/cols/z-validity bz) + per-voxel 3x3 sums for slot s
#define FINISH(s, bzv) do {                                                 \
    const float br0_ = bndRow0 * (bzv), br2_ = bndRow2 * (bzv);             \
    _Pragma("unroll")                                                       \
    for (int c_ = 0; c_ < 4; ++c_) {                                        \
        Xw[s][0][c_] *= br0_; Xw[s][2][c_] *= br2_; Xw[s][1][c_] *= (bzv);  \
    }                                                                       \
    _Pragma("unroll")                                                       \
    for (int r_ = 0; r_ < 3; ++r_) {                                        \
        Xw[s][r_][0] *= bndL; Xw[s][r_][3] *= bndR;                         \
    }                                                                       \
    _Pragma("unroll")                                                       \
    for (int q_ = 0; q_ < 2; ++q_) {                                        \
        S9[s][q_] = Xw[s][0][q_] + Xw[s][0][q_+1] + Xw[s][0][q_+2]          \
                  + Xw[s][1][q_] + Xw[s][1][q_+1] + Xw[s][1][q_+2]          \
                  + Xw[s][2][q_] + Xw[s][2][q_+1] + Xw[s][2][q_+2];         \
    }                                                                       \
} while (0)

__global__ __launch_bounds__(256, 5) void radiomics_main(
    const float* __restrict__ x, const float* __restrict__ mask,
    const float* __restrict__ gf, const float* __restrict__ lf,
    float* __restrict__ ws)
{
    __shared__ float sgf[8 * 27];
    __shared__ unsigned int shist[4 * NBINS];
    __shared__ float xred[4][28];

    const int tid = threadIdx.x;
    for (int i = tid; i < 8 * 27; i += 256) sgf[i] = gf[i];
    for (int i = tid; i < 4 * NBINS; i += 256) shist[i] = 0u;
    __syncthreads();

    // ---- weight extraction (all results forced uniform -> SGPRs) ----
    // Gabor: z-separable (outer plane = gz0*center + df_f) + point-symmetric
    // in-plane (5-tap). Fit from ACTUAL weights; validated R2-R11 absmax 3.8e-6.
    float Cs[8][5], df[8], gz0;
    {
        float asum = 0.f, mOa[8], mCa[8];
#pragma unroll
        for (int f = 0; f < 8; ++f) {
            float C9[9];
            float mC = 0.f, mO = 0.f;
#pragma unroll
            for (int k = 0; k < 9; ++k) {
                C9[k] = sgf[f * 27 + 9 + k];
                mC += C9[k];
                mO += sgf[f * 27 + k];
            }
            mC *= (1.f / 9.f); mO *= (1.f / 9.f);
            float cov = 0.f, var = 0.f;
#pragma unroll
            for (int k = 0; k < 9; ++k) {
                float c = C9[k] - mC, o = sgf[f * 27 + k] - mO;
                cov += c * o; var += c * c;
            }
            asum += cov / var; mOa[f] = mO; mCa[f] = mC;
#pragma unroll
            for (int j = 0; j < 4; ++j)
                Cs[f][j] = rfl(0.5f * (C9[j] + C9[8 - j]));
            Cs[f][4] = rfl(C9[4]);
        }
        gz0 = rfl(asum * 0.125f);
#pragma unroll
        for (int f = 0; f < 8; ++f) df[f] = rfl(mOa[f] - gz0 * mCa[f]);
    }
    // LBP weights (support = center + one axis neighbor), direct global reads
    float lwc[6], lwn[6];
    {
        const int nbidx[6] = {22, 4, 16, 10, 14, 12};
#pragma unroll
        for (int f = 0; f < 6; ++f) {
            lwc[f] = rfl(lf[f * 27 + 13]);
            lwn[f] = rfl(lf[f * 27 + nbidx[f]]);
        }
    }

    // ---- coordinates: 2 x-voxels per thread; tile 32x * 16y ----
    const int b  = blockIdx.z;
    const int z0 = blockIdx.y * CZ;
    const int tx = tid & 15, ty = tid >> 4;
    const int gx = (blockIdx.x % 5) * 32 + tx * 2;
    const int gy = (blockIdx.x / 5) * 16 + ty;

    const float* __restrict__ xbb = x    + (size_t)b * NVOX;
    const float* __restrict__ mbb = mask + (size_t)b * NVOX;

    const int gy0 = (gy > 0) ? gy - 1 : 0;
    const int gy2 = (gy + 1 < H_) ? gy + 1 : H_ - 1;
    const int rowoff[3] = { gy0 * W_, gy * W_, gy2 * W_ };
    const float bndRow0 = (gy > 0) ? 1.f : 0.f;
    const float bndRow2 = (gy + 1 < H_) ? 1.f : 0.f;
    const int xL = (gx > 0) ? gx - 1 : 0;
    const int xR = (gx + 2 < W_) ? gx + 2 : W_ - 1;
    const float bndL = (gx > 0) ? 1.f : 0.f;
    const float bndR = (gx + 2 < W_) ? 1.f : 0.f;
    const int moff  = gy * W_ + gx;
    const int myoff = gy2 * W_ + gx;
    const int mxoff = gy * W_ + xR;
    const float bym = bndRow2, bxm = bndR;

    float Xw[4][3][4];   // rotating z-slots, 3 y-rows, 4 x-cols
    float S9[4][2];      // per-slot per-voxel 3x3 sums
    float Mq[4][2];      // per-slot center mask pair
    f2    myq[2];        // prefetched y+1 neighbor-mask pairs
    float mxq[2];        // prefetched x+2 neighbor mask
    float acc[22];       // 0..4 moments, 5..12 gabor, 13..15 glcm_n,
                         // 16..18 con, 19..21 hom
    unsigned int lbppack = 0u;   // 6 x 5-bit LBP counters (max 16/chunk)
#pragma unroll
    for (int q = 0; q < 22; ++q) acc[q] = 0.f;

    // init slots: 0 = z0-1 (finished), 1 = z0 (finished), 2 = z0+1 (raw)
    if (z0 == 0) {
#pragma unroll
        for (int r = 0; r < 3; ++r)
#pragma unroll
            for (int c = 0; c < 4; ++c) Xw[0][r][c] = 0.f;
        S9[0][0] = S9[0][1] = 0.f;
    } else {
        LOADP(0, (z0 - 1) * HW_);
        FINISH(0, 1.f);
    }
    LOADP(1, z0 * HW_);
    FINISH(1, 1.f);
    {
        f2 mm = *(const f2*)(mbb + z0 * HW_ + moff);
        Mq[1][0] = (mm.x > 0.5f) ? 1.f : 0.f;
        Mq[1][1] = (mm.y > 0.5f) ? 1.f : 0.f;
    }
    LOADP(2, (z0 + 1) * HW_);      // z0+1 <= 89 < 96 always valid
    {
        f2 mm = *(const f2*)(mbb + (z0 + 1) * HW_ + moff);
        Mq[2][0] = mm.x; Mq[2][1] = mm.y;    // raw
    }
    Mq[0][0] = Mq[0][1] = 0.f;
    myq[0] = *(const f2*)(mbb + z0 * HW_ + myoff);
    mxq[0] = mbb[z0 * HW_ + mxoff];

    int zc   = z0 * HW_;
    int zpre = (z0 + 2) * HW_;

#pragma unroll 1
    for (int i0 = 0; i0 < CZ; i0 += 4) {
#pragma unroll
        for (int j = 0; j < 4; ++j) {
            const int c0 = j, c1 = (j + 1) & 3, c2 = (j + 2) & 3, c3 = (j + 3) & 3;
            const int cur = j & 1, nxt = cur ^ 1;

            // --- branchless prefetch: plane z+2 (clamped) + masks z+1 ---
            const int zpe = (zpre < NVOX) ? zpre : LASTP;     // uniform select
            LOADP(c3, zpe);
            {
                f2 mm = *(const f2*)(mbb + zpe + moff);
                Mq[c3][0] = mm.x; Mq[c3][1] = mm.y;           // raw
            }
            const int zn = (zc + HW_ < NVOX) ? zc + HW_ : LASTP;
            myq[nxt] = *(const f2*)(mbb + zn + myoff);
            mxq[nxt] = mbb[zn + mxoff];

            // --- finish plane z+1 (validity recomputed: z+1 < D) ---
            const float bzc = (zc + HW_ < NVOX) ? 1.f : 0.f;
            FINISH(c2, bzc);
            Mq[c2][0] = (Mq[c2][0] * bzc > 0.5f) ? 1.f : 0.f;
            Mq[c2][1] = (Mq[c2][1] * bzc > 0.5f) ? 1.f : 0.f;

            // T = X(z) + gz0*(X(z-1)+X(z+1)), shared by both voxels/filters
            float T6[3][4];
#pragma unroll
            for (int r = 0; r < 3; ++r)
#pragma unroll
                for (int c = 0; c < 4; ++c)
                    T6[r][c] = fmaf(gz0, Xw[c0][r][c] + Xw[c2][r][c], Xw[c1][r][c]);

            const f2 my2 = myq[cur];
            const float mxs = mxq[cur];

#pragma unroll
            for (int q = 0; q < 2; ++q) {
                const float v  = Xw[c1][1][q + 1];
                const float mc = Mq[c1][q];

                // moments
                acc[0] += mc;
                float mv  = mc * v;  acc[1] += mv;
                float mv2 = mv * v;  acc[2] += mv2;
                float mv3 = mv2 * v; acc[3] += mv3;
                acc[4] += mv3 * v;

                // histogram (wave-split)
                if (mc > 0.5f && v >= -1.f && v <= 1.f) {
                    int bi = (int)floorf((v + 1.f) * (NBINS * 0.5f));
                    bi = min(max(bi, 0), NBINS - 1);
                    atomicAdd(&shist[(tid >> 6) * NBINS + bi], 1u);
                }

                // gabor: point-symmetric 5-tap dot + df*Sigma2
                float P0 = T6[0][q]     + T6[2][q + 2];
                float P1 = T6[0][q + 1] + T6[2][q + 1];
                float P2 = T6[0][q + 2] + T6[2][q];
                float P3 = T6[1][q]     + T6[1][q + 2];
                float ctr = T6[1][q + 1];
                float S2 = S9[c0][q] + S9[c2][q];
#pragma unroll
                for (int f = 0; f < 8; ++f) {
                    float ds = df[f] * S2;
                    ds = fmaf(Cs[f][0], P0, ds);
                    ds = fmaf(Cs[f][1], P1, ds);
                    ds = fmaf(Cs[f][2], P2, ds);
                    ds = fmaf(Cs[f][3], P3, ds);
                    ds = fmaf(Cs[f][4], ctr, ds);
                    acc[5 + f] = fmaf(fabsf(ds), mc, acc[5 + f]);
                }

                // lbp packed counts (gate via l*mc: mc==0 -> l==0 -> not >0)
                const float nb[6] = { Xw[c2][1][q + 1], Xw[c0][1][q + 1],
                                      Xw[c1][2][q + 1], Xw[c1][0][q + 1],
                                      Xw[c1][1][q + 2], Xw[c1][1][q] };
#pragma unroll
                for (int f = 0; f < 6; ++f) {
                    float l = fmaf(lwc[f], v, lwn[f] * nb[f]) * mc;
                    lbppack += (l > 0.f) ? (1u << (5 * f)) : 0u;
                }

                // glcm proxy
                {   // D axis (Mq[c2] already 0 past z-boundary)
                    float mp = mc * Mq[c2][q];
                    float d = v - Xw[c2][1][q + 1], dd = d * d;
                    acc[13] += mp;
                    acc[16] = fmaf(mp, dd, acc[16]);
                    acc[19] = fmaf(mp, __builtin_amdgcn_rcpf(1.f + dd), acc[19]);
                }
                {   // H axis
                    float mr = (q == 0) ? my2.x : my2.y;
                    float mp = mc * (((mr > 0.5f) ? 1.f : 0.f) * bym);
                    float d = v - Xw[c1][2][q + 1], dd = d * d;
                    acc[14] += mp;
                    acc[17] = fmaf(mp, dd, acc[17]);
                    acc[20] = fmaf(mp, __builtin_amdgcn_rcpf(1.f + dd), acc[20]);
                }
                {   // W axis
                    float mnr = (q == 0) ? Mq[c1][1] : (((mxs > 0.5f) ? 1.f : 0.f) * bxm);
                    float mp = mc * mnr;
                    float d = v - Xw[c1][1][q + 2], dd = d * d;
                    acc[15] += mp;
                    acc[18] = fmaf(mp, dd, acc[18]);
                    acc[21] = fmaf(mp, __builtin_amdgcn_rcpf(1.f + dd), acc[21]);
                }
            }
            zc += HW_; zpre += HW_;
        }
    }

    // expand to canonical 28-quantity order
    float accx[28];
#pragma unroll
    for (int q = 0; q < 13; ++q) accx[q] = acc[q];
#pragma unroll
    for (int f = 0; f < 6; ++f)
        accx[13 + f] = (float)((lbppack >> (5 * f)) & 31u);
#pragma unroll
    for (int a = 0; a < 9; ++a) accx[19 + a] = acc[13 + a];

    // ---- block reduction + partial store (no atomics, unique slot) ----
#pragma unroll
    for (int q = 0; q < 28; ++q) {
        float s = accx[q];
#pragma unroll
        for (int o = 32; o > 0; o >>= 1)
            s += __shfl_down(s, o, 64);
        accx[q] = s;
    }
    const int lane = tid & 63, wid = tid >> 6;
    if (lane == 0) {
#pragma unroll
        for (int q = 0; q < 28; ++q) xred[wid][q] = accx[q];
    }
    __syncthreads();

    const int slot = blockIdx.x + NTILE * blockIdx.y;    // 0..599
    float* wsb = ws + (size_t)b * NQ * NSLOTS;
    if (tid < 28) {
        float s = xred[0][tid] + xred[1][tid] + xred[2][tid] + xred[3][tid];
        wsb[tid * NSLOTS + slot] = s;
    } else if (tid < NQ) {
        int h = tid - 28;
        unsigned int c = shist[h] + shist[NBINS + h]
                       + shist[2 * NBINS + h] + shist[3 * NBINS + h];
        wsb[tid * NSLOTS + slot] = (float)c;
    }
}

// Fused tail: one block per batch (512 threads = 8 waves).
__global__ __launch_bounds__(512) void radiomics_tail(
    const float* __restrict__ ws, float* __restrict__ out)
{
    __shared__ double fin[NQ];
    __shared__ double entp[NBINS];
    __shared__ double sh_hsum;
    const int b = blockIdx.x, tid = threadIdx.x;
    const int wave = tid >> 6, lane = tid & 63;

    for (int q = wave; q < NQ; q += 8) {
        const float* p = ws + ((size_t)b * NQ + q) * NSLOTS;
        double s = 0.0;
#pragma unroll
        for (int k = 0; k < 10; ++k) {
            int idx = lane + 64 * k;
            if (idx < NSLOTS) s += (double)p[idx];
        }
#pragma unroll
        for (int o = 32; o > 0; o >>= 1)
            s += __shfl_down(s, o, 64);
        if (lane == 0) fin[q] = s;
    }
    __syncthreads();

    if (tid == 0) {
        double h = 0.0;
        for (int k = 0; k < NBINS; ++k) h += fin[28 + k];
        sh_hsum = h + 1e-8;
    }
    __syncthreads();

    if (tid < NBINS) {
        double p = fin[28 + tid] / sh_hsum;
        entp[tid] = -p * log(p + 1e-8);
    }
    __syncthreads();

    if (tid == 0) {
        const double n  = fin[0];
        const double nn = fmax(n, 1.0);
        const double s1 = fin[1], s2 = fin[2], s3 = fin[3], s4 = fin[4];
        const double mu = s1 / nn;
        const double M2 = s2 - 2.0 * mu * s1 + mu * mu * n;
        const double M3 = s3 - 3.0 * mu * s2 + 3.0 * mu * mu * s1 - mu * mu * mu * n;
        const double M4 = s4 - 4.0 * mu * s3 + 6.0 * mu * mu * s2
                          - 4.0 * mu * mu * mu * s1 + mu * mu * mu * mu * n;
        const double var   = M2 / fmax(n - 1.0, 1.0);
        const double sigma = sqrt(var) + 1e-8;
        const double skew  = M3 / (sigma * sigma * sigma) / nn;
        const double kurt  = M4 / (sigma * sigma * sigma * sigma) / nn - 3.0;

        double ent = 0.0;
        for (int k = 0; k < NBINS; ++k) ent += entp[k];

        const double valid = (n >= 10.0) ? 1.0 : 0.0;
        float* ob = out + b * 25;
        ob[0] = (float)(mu * valid);
        ob[1] = (float)(sigma * valid);
        ob[2] = (float)(skew * valid);
        ob[3] = (float)(kurt * valid);
        ob[4] = (float)(ent * valid);

        const double lung = fmax(n, 1.0);
        for (int f = 0; f < 8; ++f) ob[5 + f]  = (float)(fin[5 + f] / lung);
        for (int f = 0; f < 6; ++f) ob[13 + f] = (float)(fin[13 + f] / lung);

        for (int ax = 0; ax < 3; ++ax) {
            double s  = fin[19 + ax];
            double ss = fmax(s, 1.0);
            double ok = (s >= 4.0) ? 1.0 : 0.0;
            ob[19 + 2 * ax]     = (float)(fin[22 + ax] / ss * ok);
            ob[19 + 2 * ax + 1] = (float)(fin[25 + ax] / ss * ok);
        }
    }
}

extern "C" void kernel_launch(void* const* d_in, const int* in_sizes, int n_in,
                              void* d_out, int out_size, void* d_ws, size_t ws_size,
                              hipStream_t stream)
{
    const float* x    = (const float*)d_in[0];
    const float* mask = (const float*)d_in[1];
    const float* gf   = (const float*)d_in[2];
    const float* lf   = (const float*)d_in[3];
    float* out = (float*)d_out;
    float* ws  = (float*)d_ws;    // 4*78*600 floats = 748.8 KB, fully overwritten

    dim3 grid(NTILE, NCHUNK, B_);   // 2400 blocks
    radiomics_main<<<grid, 256, 0, stream>>>(x, mask, gf, lf, ws);
    radiomics_tail<<<B_, 512, 0, stream>>>(ws, out);
}

// Round 13
// 173.406 us; speedup vs baseline: 4.7678x; 4.7678x over previous
//
#include <hip/hip_runtime.h>
#include <math.h>

// Problem constants (fixed by setup_inputs)
#define B_    4
#define D_    96
#define H_    160
#define W_    160
#define HW_   (H_ * W_)
#define NVOX  (D_ * H_ * W_)
#define NBINS 50
#define NQ    78        // 5 moments + 8 gab + 6 lbp + 9 glcm + 50 hist
#define CZ    12
#define NCHUNK (D_ / CZ)          // 8
#define NTILE 50                  // x-y tiles (32x16 over 160x160)
#define NSLOTS (NTILE * NCHUNK)   // 400 partial slots per batch
#define LASTP ((D_ - 1) * HW_)

typedef float f2 __attribute__((ext_vector_type(2)));

// readfirstlane a float into an SGPR-resident uniform value
__device__ __forceinline__ float rfl(float v) {
    return __uint_as_float(__builtin_amdgcn_readfirstlane(__float_as_uint(v)));
}

// load raw 3x4 window rows of plane at element offset zo into slot s
#define LOADP(s, zo) do {                                                   \
    _Pragma("unroll")                                                       \
    for (int r_ = 0; r_ < 3; ++r_) {                                        \
        Xw[s][r_][0] = xbb[(zo) + rowoff[r_] + xL];                         \
        f2 t_ = *(const f2*)(xbb + (zo) + rowoff[r_] + gx);                 \
        Xw[s][r_][1] = t_.x; Xw[s][r_][2] = t_.y;                           \
        Xw[s][r_][3] = xbb[(zo) + rowoff[r_] + xR];                         \
    }                                                                       \
} while (0)

// boundary zeroing (rows/cols/z-validity bz) + per-voxel 3x3 sums for slot s
#define FINISH(s, bzv) do {                                                 \
    const float br0_ = bndRow0 * (bzv), br2_ = bndRow2 * (bzv);             \
    _Pragma("unroll")                                                       \
    for (int c_ = 0; c_ < 4; ++c_) {                                        \
        Xw[s][0][c_] *= br0_; Xw[s][2][c_] *= br2_; Xw[s][1][c_] *= (bzv);  \
    }                                                                       \
    _Pragma("unroll")                                                       \
    for (int r_ = 0; r_ < 3; ++r_) {                                        \
        Xw[s][r_][0] *= bndL; Xw[s][r_][3] *= bndR;                         \
    }                                                                       \
    _Pragma("unroll")                                                       \
    for (int q_ = 0; q_ < 2; ++q_) {                                        \
        S9[s][q_] = Xw[s][0][q_] + Xw[s][0][q_+1] + Xw[s][0][q_+2]          \
                  + Xw[s][1][q_] + Xw[s][1][q_+1] + Xw[s][1][q_+2]          \
                  + Xw[s][2][q_] + Xw[s][2][q_+1] + Xw[s][2][q_+2];         \
    }                                                                       \
} while (0)

__global__ __launch_bounds__(256) void radiomics_main(
    const float* __restrict__ x, const float* __restrict__ mask,
    const float* __restrict__ gf, const float* __restrict__ lf,
    float* __restrict__ ws)
{
    __shared__ float sgf[8 * 27];
    __shared__ unsigned int shist[4 * NBINS];
    __shared__ float xred[4][28];

    const int tid = threadIdx.x;
    for (int i = tid; i < 8 * 27; i += 256) sgf[i] = gf[i];
    for (int i = tid; i < 4 * NBINS; i += 256) shist[i] = 0u;
    __syncthreads();

    // ---- weight extraction (all results forced uniform -> SGPRs) ----
    // Gabor: z-separable (outer plane = gz0*center + df_f) + point-symmetric
    // in-plane (5-tap). Fit from ACTUAL weights; validated R2-R12 absmax 3.8e-6.
    float Cs[8][5], df[8], gz0;
    {
        float asum = 0.f, mOa[8], mCa[8];
#pragma unroll
        for (int f = 0; f < 8; ++f) {
            float C9[9];
            float mC = 0.f, mO = 0.f;
#pragma unroll
            for (int k = 0; k < 9; ++k) {
                C9[k] = sgf[f * 27 + 9 + k];
                mC += C9[k];
                mO += sgf[f * 27 + k];
            }
            mC *= (1.f / 9.f); mO *= (1.f / 9.f);
            float cov = 0.f, var = 0.f;
#pragma unroll
            for (int k = 0; k < 9; ++k) {
                float c = C9[k] - mC, o = sgf[f * 27 + k] - mO;
                cov += c * o; var += c * c;
            }
            asum += cov / var; mOa[f] = mO; mCa[f] = mC;
#pragma unroll
            for (int j = 0; j < 4; ++j)
                Cs[f][j] = rfl(0.5f * (C9[j] + C9[8 - j]));
            Cs[f][4] = rfl(C9[4]);
        }
        gz0 = rfl(asum * 0.125f);
#pragma unroll
        for (int f = 0; f < 8; ++f) df[f] = rfl(mOa[f] - gz0 * mCa[f]);
    }
    // LBP weights (support = center + one axis neighbor), direct global reads
    float lwc[6], lwn[6];
    {
        const int nbidx[6] = {22, 4, 16, 10, 14, 12};
#pragma unroll
        for (int f = 0; f < 6; ++f) {
            lwc[f] = rfl(lf[f * 27 + 13]);
            lwn[f] = rfl(lf[f * 27 + nbidx[f]]);
        }
    }

    // ---- coordinates: 2 x-voxels per thread; tile 32x * 16y ----
    const int b  = blockIdx.z;
    const int z0 = blockIdx.y * CZ;
    const int tx = tid & 15, ty = tid >> 4;
    const int gx = (blockIdx.x % 5) * 32 + tx * 2;
    const int gy = (blockIdx.x / 5) * 16 + ty;

    const float* __restrict__ xbb = x    + (size_t)b * NVOX;
    const float* __restrict__ mbb = mask + (size_t)b * NVOX;

    const int gy0 = (gy > 0) ? gy - 1 : 0;
    const int gy2 = (gy + 1 < H_) ? gy + 1 : H_ - 1;
    const int rowoff[3] = { gy0 * W_, gy * W_, gy2 * W_ };
    const float bndRow0 = (gy > 0) ? 1.f : 0.f;
    const float bndRow2 = (gy + 1 < H_) ? 1.f : 0.f;
    const int xL = (gx > 0) ? gx - 1 : 0;
    const int xR = (gx + 2 < W_) ? gx + 2 : W_ - 1;
    const float bndL = (gx > 0) ? 1.f : 0.f;
    const float bndR = (gx + 2 < W_) ? 1.f : 0.f;
    const int moff  = gy * W_ + gx;
    const int myoff = gy2 * W_ + gx;
    const int mxoff = gy * W_ + xR;
    const float bym = bndRow2, bxm = bndR;

    float Xw[4][3][4];   // rotating z-slots, 3 y-rows, 4 x-cols
    float S9[4][2];      // per-slot per-voxel 3x3 sums
    float Mq[4][2];      // per-slot center mask pair
    float bzs[4];        // per-slot z-validity
    f2    myq[2];        // prefetched y+1 neighbor-mask pairs
    float mxq[2];        // prefetched x+2 neighbor mask
    float acc[28];
#pragma unroll
    for (int q = 0; q < 28; ++q) acc[q] = 0.f;
    bzs[0] = bzs[1] = bzs[2] = 1.f;

    // init slots: 0 = z0-1 (finished), 1 = z0 (finished), 2 = z0+1 (raw)
    if (z0 == 0) {
#pragma unroll
        for (int r = 0; r < 3; ++r)
#pragma unroll
            for (int c = 0; c < 4; ++c) Xw[0][r][c] = 0.f;
        S9[0][0] = S9[0][1] = 0.f;
    } else {
        LOADP(0, (z0 - 1) * HW_);
        FINISH(0, 1.f);
    }
    LOADP(1, z0 * HW_);
    FINISH(1, 1.f);
    {
        f2 mm = *(const f2*)(mbb + z0 * HW_ + moff);
        Mq[1][0] = (mm.x > 0.5f) ? 1.f : 0.f;
        Mq[1][1] = (mm.y > 0.5f) ? 1.f : 0.f;
    }
    LOADP(2, (z0 + 1) * HW_);      // z0+1 <= 85 < 96 always valid
    {
        f2 mm = *(const f2*)(mbb + (z0 + 1) * HW_ + moff);
        Mq[2][0] = mm.x; Mq[2][1] = mm.y;    // raw
    }
    Mq[0][0] = Mq[0][1] = 0.f;
    myq[0] = *(const f2*)(mbb + z0 * HW_ + myoff);
    mxq[0] = mbb[z0 * HW_ + mxoff];

    int zc   = z0 * HW_;
    int zpre = (z0 + 2) * HW_;

#pragma unroll 1
    for (int i0 = 0; i0 < CZ; i0 += 4) {
#pragma unroll
        for (int j = 0; j < 4; ++j) {
            const int c0 = j, c1 = (j + 1) & 3, c2 = (j + 2) & 3, c3 = (j + 3) & 3;
            const int cur = j & 1, nxt = cur ^ 1;

            // --- branchless prefetch: plane z+2 (clamped) + masks z+1 ---
            const int zpe = (zpre < NVOX) ? zpre : LASTP;     // uniform select
            bzs[c3] = (zpre < NVOX) ? 1.f : 0.f;
            LOADP(c3, zpe);
            {
                f2 mm = *(const f2*)(mbb + zpe + moff);
                Mq[c3][0] = mm.x; Mq[c3][1] = mm.y;           // raw
            }
            const int zn = (zc + HW_ < NVOX) ? zc + HW_ : LASTP;
            myq[nxt] = *(const f2*)(mbb + zn + myoff);
            mxq[nxt] = mbb[zn + mxoff];

            // --- finish plane z+1 ---
            FINISH(c2, bzs[c2]);
            Mq[c2][0] = (Mq[c2][0] * bzs[c2] > 0.5f) ? 1.f : 0.f;
            Mq[c2][1] = (Mq[c2][1] * bzs[c2] > 0.5f) ? 1.f : 0.f;

            // T = X(z) + gz0*(X(z-1)+X(z+1)), shared by both voxels/filters
            float T6[3][4];
#pragma unroll
            for (int r = 0; r < 3; ++r)
#pragma unroll
                for (int c = 0; c < 4; ++c)
                    T6[r][c] = fmaf(gz0, Xw[c0][r][c] + Xw[c2][r][c], Xw[c1][r][c]);

            const f2 my2 = myq[cur];
            const float mxs = mxq[cur];

#pragma unroll
            for (int q = 0; q < 2; ++q) {
                const float v  = Xw[c1][1][q + 1];
                const float mc = Mq[c1][q];

                // moments
                acc[0] += mc;
                float mv  = mc * v;  acc[1] += mv;
                float mv2 = mv * v;  acc[2] += mv2;
                float mv3 = mv2 * v; acc[3] += mv3;
                acc[4] += mv3 * v;

                // histogram (wave-split)
                if (mc > 0.5f && v >= -1.f && v <= 1.f) {
                    int bi = (int)floorf((v + 1.f) * (NBINS * 0.5f));
                    bi = min(max(bi, 0), NBINS - 1);
                    atomicAdd(&shist[(tid >> 6) * NBINS + bi], 1u);
                }

                // gabor: point-symmetric 5-tap dot + df*Sigma2
                float P0 = T6[0][q]     + T6[2][q + 2];
                float P1 = T6[0][q + 1] + T6[2][q + 1];
                float P2 = T6[0][q + 2] + T6[2][q];
                float P3 = T6[1][q]     + T6[1][q + 2];
                float ctr = T6[1][q + 1];
                float S2 = S9[c0][q] + S9[c2][q];
#pragma unroll
                for (int f = 0; f < 8; ++f) {
                    float ds = df[f] * S2;
                    ds = fmaf(Cs[f][0], P0, ds);
                    ds = fmaf(Cs[f][1], P1, ds);
                    ds = fmaf(Cs[f][2], P2, ds);
                    ds = fmaf(Cs[f][3], P3, ds);
                    ds = fmaf(Cs[f][4], ctr, ds);
                    acc[5 + f] = fmaf(fabsf(ds), mc, acc[5 + f]);
                }

                // lbp (2-tap, actual weights): z+1, z-1, y+1, y-1, x+1, x-1
                const float nb[6] = { Xw[c2][1][q + 1], Xw[c0][1][q + 1],
                                      Xw[c1][2][q + 1], Xw[c1][0][q + 1],
                                      Xw[c1][1][q + 2], Xw[c1][1][q] };
#pragma unroll
                for (int f = 0; f < 6; ++f) {
                    float l = fmaf(lwc[f], v, lwn[f] * nb[f]);
                    acc[13 + f] += (l > 0.f) ? mc : 0.f;
                }

                // glcm proxy
                {   // D axis (Mq[c2] already 0 past z-boundary)
                    float mp = mc * Mq[c2][q];
                    float d = v - Xw[c2][1][q + 1], dd = d * d;
                    acc[19] += mp;
                    acc[22] = fmaf(mp, dd, acc[22]);
                    acc[25] = fmaf(mp, __builtin_amdgcn_rcpf(1.f + dd), acc[25]);
                }
                {   // H axis
                    float mr = (q == 0) ? my2.x : my2.y;
                    float mp = mc * (((mr > 0.5f) ? 1.f : 0.f) * bym);
                    float d = v - Xw[c1][2][q + 1], dd = d * d;
                    acc[20] += mp;
                    acc[23] = fmaf(mp, dd, acc[23]);
                    acc[26] = fmaf(mp, __builtin_amdgcn_rcpf(1.f + dd), acc[26]);
                }
                {   // W axis
                    float mnr = (q == 0) ? Mq[c1][1] : (((mxs > 0.5f) ? 1.f : 0.f) * bxm);
                    float mp = mc * mnr;
                    float d = v - Xw[c1][1][q + 2], dd = d * d;
                    acc[21] += mp;
                    acc[24] = fmaf(mp, dd, acc[24]);
                    acc[27] = fmaf(mp, __builtin_amdgcn_rcpf(1.f + dd), acc[27]);
                }
            }
            zc += HW_; zpre += HW_;
        }
    }

    // ---- block reduction + partial store (no atomics, unique slot) ----
#pragma unroll
    for (int q = 0; q < 28; ++q) {
        float s = acc[q];
#pragma unroll
        for (int o = 32; o > 0; o >>= 1)
            s += __shfl_down(s, o, 64);
        acc[q] = s;
    }
    const int lane = tid & 63, wid = tid >> 6;
    if (lane == 0) {
#pragma unroll
        for (int q = 0; q < 28; ++q) xred[wid][q] = acc[q];
    }
    __syncthreads();

    const int slot = blockIdx.x + NTILE * blockIdx.y;    // 0..399
    float* wsb = ws + (size_t)b * NQ * NSLOTS;
    if (tid < 28) {
        float s = xred[0][tid] + xred[1][tid] + xred[2][tid] + xred[3][tid];
        wsb[tid * NSLOTS + slot] = s;
    } else if (tid < NQ) {
        int h = tid - 28;
        unsigned int c = shist[h] + shist[NBINS + h]
                       + shist[2 * NBINS + h] + shist[3 * NBINS + h];
        wsb[tid * NSLOTS + slot] = (float)c;
    }
}

// Fused tail: one block per batch (512 threads = 8 waves).
__global__ __launch_bounds__(512) void radiomics_tail(
    const float* __restrict__ ws, float* __restrict__ out)
{
    __shared__ double fin[NQ];
    __shared__ double entp[NBINS];
    __shared__ double sh_hsum;
    const int b = blockIdx.x, tid = threadIdx.x;
    const int wave = tid >> 6, lane = tid & 63;

    for (int q = wave; q < NQ; q += 8) {
        const float* p = ws + ((size_t)b * NQ + q) * NSLOTS;
        double s = 0.0;
#pragma unroll
        for (int k = 0; k < 7; ++k) {
            int idx = lane + 64 * k;
            if (idx < NSLOTS) s += (double)p[idx];
        }
#pragma unroll
        for (int o = 32; o > 0; o >>= 1)
            s += __shfl_down(s, o, 64);
        if (lane == 0) fin[q] = s;
    }
    __syncthreads();

    if (tid == 0) {
        double h = 0.0;
        for (int k = 0; k < NBINS; ++k) h += fin[28 + k];
        sh_hsum = h + 1e-8;
    }
    __syncthreads();

    if (tid < NBINS) {
        double p = fin[28 + tid] / sh_hsum;
        entp[tid] = -p * log(p + 1e-8);
    }
    __syncthreads();

    if (tid == 0) {
        const double n  = fin[0];
        const double nn = fmax(n, 1.0);
        const double s1 = fin[1], s2 = fin[2], s3 = fin[3], s4 = fin[4];
        const double mu = s1 / nn;
        const double M2 = s2 - 2.0 * mu * s1 + mu * mu * n;
        const double M3 = s3 - 3.0 * mu * s2 + 3.0 * mu * mu * s1 - mu * mu * mu * n;
        const double M4 = s4 - 4.0 * mu * s3 + 6.0 * mu * mu * s2
                          - 4.0 * mu * mu * mu * s1 + mu * mu * mu * mu * n;
        const double var   = M2 / fmax(n - 1.0, 1.0);
        const double sigma = sqrt(var) + 1e-8;
        const double skew  = M3 / (sigma * sigma * sigma) / nn;
        const double kurt  = M4 / (sigma * sigma * sigma * sigma) / nn - 3.0;

        double ent = 0.0;
        for (int k = 0; k < NBINS; ++k) ent += entp[k];

        const double valid = (n >= 10.0) ? 1.0 : 0.0;
        float* ob = out + b * 25;
        ob[0] = (float)(mu * valid);
        ob[1] = (float)(sigma * valid);
        ob[2] = (float)(skew * valid);
        ob[3] = (float)(kurt * valid);
        ob[4] = (float)(ent * valid);

        const double lung = fmax(n, 1.0);
        for (int f = 0; f < 8; ++f) ob[5 + f]  = (float)(fin[5 + f] / lung);
        for (int f = 0; f < 6; ++f) ob[13 + f] = (float)(fin[13 + f] / lung);

        for (int ax = 0; ax < 3; ++ax) {
            double s  = fin[19 + ax];
            double ss = fmax(s, 1.0);
            double ok = (s >= 4.0) ? 1.0 : 0.0;
            ob[19 + 2 * ax]     = (float)(fin[22 + ax] / ss * ok);
            ob[19 + 2 * ax + 1] = (float)(fin[25 + ax] / ss * ok);
        }
    }
}

extern "C" void kernel_launch(void* const* d_in, const int* in_sizes, int n_in,
                              void* d_out, int out_size, void* d_ws, size_t ws_size,
                              hipStream_t stream)
{
    const float* x    = (const float*)d_in[0];
    const float* mask = (const float*)d_in[1];
    const float* gf   = (const float*)d_in[2];
    const float* lf   = (const float*)d_in[3];
    float* out = (float*)d_out;
    float* ws  = (float*)d_ws;    // 4*78*400 floats = 499.2 KB, fully overwritten

    dim3 grid(NTILE, NCHUNK, B_);   // 1600 blocks
    radiomics_main<<<grid, 256, 0, stream>>>(x, mask, gf, lf, ws);
    radiomics_tail<<<B_, 512, 0, stream>>>(ws, out);
}

// Round 14
// 167.363 us; speedup vs baseline: 4.9400x; 1.0361x over previous
//
#include <hip/hip_runtime.h>
#include <math.h>

// Problem constants (fixed by setup_inputs)
#define B_    4
#define D_    96
#define H_    160
#define W_    160
#define HW_   (H_ * W_)
#define NVOX  (D_ * H_ * W_)
#define NBINS 50
#define NQ    78        // 5 moments + 8 gab + 6 lbp + 9 glcm + 50 hist
#define CZ    16
#define NCHUNK (D_ / CZ)          // 6
#define NTILE 50                  // x-y tiles (32x16 over 160x160)
#define NSLOTS (NTILE * NCHUNK)   // 300 partial slots per batch
#define LASTP ((D_ - 1) * HW_)

typedef float f2 __attribute__((ext_vector_type(2)));

// readfirstlane a float into an SGPR-resident uniform value
__device__ __forceinline__ float rfl(float v) {
    return __uint_as_float(__builtin_amdgcn_readfirstlane(__float_as_uint(v)));
}

// load raw 3x4 window rows of plane at element offset zo into slot s
#define LOADP(s, zo) do {                                                   \
    _Pragma("unroll")                                                       \
    for (int r_ = 0; r_ < 3; ++r_) {                                        \
        Xw[s][r_][0] = xbb[(zo) + rowoff[r_] + xL];                         \
        f2 t_ = *(const f2*)(xbb + (zo) + rowoff[r_] + gx);                 \
        Xw[s][r_][1] = t_.x; Xw[s][r_][2] = t_.y;                           \
        Xw[s][r_][3] = xbb[(zo) + rowoff[r_] + xR];                         \
    }                                                                       \
} while (0)

// boundary zeroing (rows/cols/z-validity bz) + per-voxel 3x3 sums for slot s
#define FINISH(s, bzv) do {                                                 \
    const float br0_ = bndRow0 * (bzv), br2_ = bndRow2 * (bzv);             \
    _Pragma("unroll")                                                       \
    for (int c_ = 0; c_ < 4; ++c_) {                                        \
        Xw[s][0][c_] *= br0_; Xw[s][2][c_] *= br2_; Xw[s][1][c_] *= (bzv);  \
    }                                                                       \
    _Pragma("unroll")                                                       \
    for (int r_ = 0; r_ < 3; ++r_) {                                        \
        Xw[s][r_][0] *= bndL; Xw[s][r_][3] *= bndR;                         \
    }                                                                       \
    _Pragma("unroll")                                                       \
    for (int q_ = 0; q_ < 2; ++q_) {                                        \
        S9[s][q_] = Xw[s][0][q_] + Xw[s][0][q_+1] + Xw[s][0][q_+2]          \
                  + Xw[s][1][q_] + Xw[s][1][q_+1] + Xw[s][1][q_+2]          \
                  + Xw[s][2][q_] + Xw[s][2][q_+1] + Xw[s][2][q_+2];         \
    }                                                                       \
} while (0)

__global__ __launch_bounds__(256) void radiomics_main(
    const float* __restrict__ x, const float* __restrict__ mask,
    const float* __restrict__ gf, const float* __restrict__ lf,
    float* __restrict__ ws)
{
    __shared__ float sgf[8 * 27];
    __shared__ unsigned int shist[4 * NBINS];
    __shared__ float xred[4][28];

    const int tid = threadIdx.x;
    for (int i = tid; i < 8 * 27; i += 256) sgf[i] = gf[i];
    for (int i = tid; i < 4 * NBINS; i += 256) shist[i] = 0u;
    __syncthreads();

    // ---- weight extraction (all results forced uniform -> SGPRs) ----
    // Gabor: z-separable (outer plane = gz0*center + df_f) + point-symmetric
    // in-plane (5-tap). Fit from ACTUAL weights; validated R2-R13 absmax 3.8e-6.
    float Cs[8][5], df[8], gz0;
    {
        float asum = 0.f, mOa[8], mCa[8];
#pragma unroll
        for (int f = 0; f < 8; ++f) {
            float C9[9];
            float mC = 0.f, mO = 0.f;
#pragma unroll
            for (int k = 0; k < 9; ++k) {
                C9[k] = sgf[f * 27 + 9 + k];
                mC += C9[k];
                mO += sgf[f * 27 + k];
            }
            mC *= (1.f / 9.f); mO *= (1.f / 9.f);
            float cov = 0.f, var = 0.f;
#pragma unroll
            for (int k = 0; k < 9; ++k) {
                float c = C9[k] - mC, o = sgf[f * 27 + k] - mO;
                cov += c * o; var += c * c;
            }
            asum += cov / var; mOa[f] = mO; mCa[f] = mC;
#pragma unroll
            for (int j = 0; j < 4; ++j)
                Cs[f][j] = rfl(0.5f * (C9[j] + C9[8 - j]));
            Cs[f][4] = rfl(C9[4]);
        }
        gz0 = rfl(asum * 0.125f);
#pragma unroll
        for (int f = 0; f < 8; ++f) df[f] = rfl(mOa[f] - gz0 * mCa[f]);
    }
    // LBP weights (support = center + one axis neighbor), direct global reads
    float lwc[6], lwn[6];
    {
        const int nbidx[6] = {22, 4, 16, 10, 14, 12};
#pragma unroll
        for (int f = 0; f < 6; ++f) {
            lwc[f] = rfl(lf[f * 27 + 13]);
            lwn[f] = rfl(lf[f * 27 + nbidx[f]]);
        }
    }

    // ---- coordinates: 2 x-voxels per thread; tile 32x * 16y ----
    const int b  = blockIdx.z;
    const int z0 = blockIdx.y * CZ;
    const int tx = tid & 15, ty = tid >> 4;
    const int gx = (blockIdx.x % 5) * 32 + tx * 2;
    const int gy = (blockIdx.x / 5) * 16 + ty;

    const float* __restrict__ xbb = x    + (size_t)b * NVOX;
    const float* __restrict__ mbb = mask + (size_t)b * NVOX;

    const int gy0 = (gy > 0) ? gy - 1 : 0;
    const int gy2 = (gy + 1 < H_) ? gy + 1 : H_ - 1;
    const int rowoff[3] = { gy0 * W_, gy * W_, gy2 * W_ };
    const float bndRow0 = (gy > 0) ? 1.f : 0.f;
    const float bndRow2 = (gy + 1 < H_) ? 1.f : 0.f;
    const int xL = (gx > 0) ? gx - 1 : 0;
    const int xR = (gx + 2 < W_) ? gx + 2 : W_ - 1;
    const float bndL = (gx > 0) ? 1.f : 0.f;
    const float bndR = (gx + 2 < W_) ? 1.f : 0.f;
    const int moff  = gy * W_ + gx;
    const int myoff = gy2 * W_ + gx;
    const int mxoff = gy * W_ + xR;
    const float bym = bndRow2, bxm = bndR;

    float Xw[4][3][4];   // rotating z-slots, 3 y-rows, 4 x-cols
    float S9[4][2];      // per-slot per-voxel 3x3 sums
    float Mq[4][2];      // per-slot center mask pair
    float bzs[4];        // per-slot z-validity
    f2    myq[2];        // prefetched y+1 neighbor-mask pairs
    float mxq[2];        // prefetched x+2 neighbor mask
    float acc[28];
#pragma unroll
    for (int q = 0; q < 28; ++q) acc[q] = 0.f;
    bzs[0] = bzs[1] = bzs[2] = 1.f;

    // init slots: 0 = z0-1 (finished), 1 = z0 (finished), 2 = z0+1 (raw)
    if (z0 == 0) {
#pragma unroll
        for (int r = 0; r < 3; ++r)
#pragma unroll
            for (int c = 0; c < 4; ++c) Xw[0][r][c] = 0.f;
        S9[0][0] = S9[0][1] = 0.f;
    } else {
        LOADP(0, (z0 - 1) * HW_);
        FINISH(0, 1.f);
    }
    LOADP(1, z0 * HW_);
    FINISH(1, 1.f);
    {
        f2 mm = *(const f2*)(mbb + z0 * HW_ + moff);
        Mq[1][0] = (mm.x > 0.5f) ? 1.f : 0.f;
        Mq[1][1] = (mm.y > 0.5f) ? 1.f : 0.f;
    }
    LOADP(2, (z0 + 1) * HW_);      // z0+1 <= 81 < 96 always valid
    {
        f2 mm = *(const f2*)(mbb + (z0 + 1) * HW_ + moff);
        Mq[2][0] = mm.x; Mq[2][1] = mm.y;    // raw
    }
    Mq[0][0] = Mq[0][1] = 0.f;
    myq[0] = *(const f2*)(mbb + z0 * HW_ + myoff);
    mxq[0] = mbb[z0 * HW_ + mxoff];

    int zc   = z0 * HW_;
    int zpre = (z0 + 2) * HW_;

#pragma unroll 1
    for (int i0 = 0; i0 < CZ; i0 += 4) {
#pragma unroll
        for (int j = 0; j < 4; ++j) {
            const int c0 = j, c1 = (j + 1) & 3, c2 = (j + 2) & 3, c3 = (j + 3) & 3;
            const int cur = j & 1, nxt = cur ^ 1;

            // --- branchless prefetch: plane z+2 (clamped) + masks z+1 ---
            const int zpe = (zpre < NVOX) ? zpre : LASTP;     // uniform select
            bzs[c3] = (zpre < NVOX) ? 1.f : 0.f;
            LOADP(c3, zpe);
            {
                f2 mm = *(const f2*)(mbb + zpe + moff);
                Mq[c3][0] = mm.x; Mq[c3][1] = mm.y;           // raw
            }
            const int zn = (zc + HW_ < NVOX) ? zc + HW_ : LASTP;
            myq[nxt] = *(const f2*)(mbb + zn + myoff);
            mxq[nxt] = mbb[zn + mxoff];

            // --- finish plane z+1 ---
            FINISH(c2, bzs[c2]);
            Mq[c2][0] = (Mq[c2][0] * bzs[c2] > 0.5f) ? 1.f : 0.f;
            Mq[c2][1] = (Mq[c2][1] * bzs[c2] > 0.5f) ? 1.f : 0.f;

            // T = X(z) + gz0*(X(z-1)+X(z+1)), shared by both voxels/filters
            float T6[3][4];
#pragma unroll
            for (int r = 0; r < 3; ++r)
#pragma unroll
                for (int c = 0; c < 4; ++c)
                    T6[r][c] = fmaf(gz0, Xw[c0][r][c] + Xw[c2][r][c], Xw[c1][r][c]);

            const f2 my2 = myq[cur];
            const float mxs = mxq[cur];

#pragma unroll
            for (int q = 0; q < 2; ++q) {
                const float v  = Xw[c1][1][q + 1];
                const float mc = Mq[c1][q];

                // moments
                acc[0] += mc;
                float mv  = mc * v;  acc[1] += mv;
                float mv2 = mv * v;  acc[2] += mv2;
                float mv3 = mv2 * v; acc[3] += mv3;
                acc[4] += mv3 * v;

                // histogram (wave-split)
                if (mc > 0.5f && v >= -1.f && v <= 1.f) {
                    int bi = (int)floorf((v + 1.f) * (NBINS * 0.5f));
                    bi = min(max(bi, 0), NBINS - 1);
                    atomicAdd(&shist[(tid >> 6) * NBINS + bi], 1u);
                }

                // gabor: point-symmetric 5-tap dot + df*Sigma2
                float P0 = T6[0][q]     + T6[2][q + 2];
                float P1 = T6[0][q + 1] + T6[2][q + 1];
                float P2 = T6[0][q + 2] + T6[2][q];
                float P3 = T6[1][q]     + T6[1][q + 2];
                float ctr = T6[1][q + 1];
                float S2 = S9[c0][q] + S9[c2][q];
#pragma unroll
                for (int f = 0; f < 8; ++f) {
                    float ds = df[f] * S2;
                    ds = fmaf(Cs[f][0], P0, ds);
                    ds = fmaf(Cs[f][1], P1, ds);
                    ds = fmaf(Cs[f][2], P2, ds);
                    ds = fmaf(Cs[f][3], P3, ds);
                    ds = fmaf(Cs[f][4], ctr, ds);
                    acc[5 + f] = fmaf(fabsf(ds), mc, acc[5 + f]);
                }

                // lbp (2-tap, actual weights): z+1, z-1, y+1, y-1, x+1, x-1
                const float nb[6] = { Xw[c2][1][q + 1], Xw[c0][1][q + 1],
                                      Xw[c1][2][q + 1], Xw[c1][0][q + 1],
                                      Xw[c1][1][q + 2], Xw[c1][1][q] };
#pragma unroll
                for (int f = 0; f < 6; ++f) {
                    float l = fmaf(lwc[f], v, lwn[f] * nb[f]);
                    acc[13 + f] += (l > 0.f) ? mc : 0.f;
                }

                // glcm proxy
                {   // D axis (Mq[c2] already 0 past z-boundary)
                    float mp = mc * Mq[c2][q];
                    float d = v - Xw[c2][1][q + 1], dd = d * d;
                    acc[19] += mp;
                    acc[22] = fmaf(mp, dd, acc[22]);
                    acc[25] = fmaf(mp, __builtin_amdgcn_rcpf(1.f + dd), acc[25]);
                }
                {   // H axis
                    float mr = (q == 0) ? my2.x : my2.y;
                    float mp = mc * (((mr > 0.5f) ? 1.f : 0.f) * bym);
                    float d = v - Xw[c1][2][q + 1], dd = d * d;
                    acc[20] += mp;
                    acc[23] = fmaf(mp, dd, acc[23]);
                    acc[26] = fmaf(mp, __builtin_amdgcn_rcpf(1.f + dd), acc[26]);
                }
                {   // W axis
                    float mnr = (q == 0) ? Mq[c1][1] : (((mxs > 0.5f) ? 1.f : 0.f) * bxm);
                    float mp = mc * mnr;
                    float d = v - Xw[c1][1][q + 2], dd = d * d;
                    acc[21] += mp;
                    acc[24] = fmaf(mp, dd, acc[24]);
                    acc[27] = fmaf(mp, __builtin_amdgcn_rcpf(1.f + dd), acc[27]);
                }
            }
            zc += HW_; zpre += HW_;
        }
    }

    // ---- block reduction + partial store (no atomics, unique slot) ----
#pragma unroll
    for (int q = 0; q < 28; ++q) {
        float s = acc[q];
#pragma unroll
        for (int o = 32; o > 0; o >>= 1)
            s += __shfl_down(s, o, 64);
        acc[q] = s;
    }
    const int lane = tid & 63, wid = tid >> 6;
    if (lane == 0) {
#pragma unroll
        for (int q = 0; q < 28; ++q) xred[wid][q] = acc[q];
    }
    __syncthreads();

    const int slot = blockIdx.x + NTILE * blockIdx.y;    // 0..299
    float* wsb = ws + (size_t)b * NQ * NSLOTS;
    if (tid < 28) {
        float s = xred[0][tid] + xred[1][tid] + xred[2][tid] + xred[3][tid];
        wsb[tid * NSLOTS + slot] = s;
    } else if (tid < NQ) {
        int h = tid - 28;
        unsigned int c = shist[h] + shist[NBINS + h]
                       + shist[2 * NBINS + h] + shist[3 * NBINS + h];
        wsb[tid * NSLOTS + slot] = (float)c;
    }
}

// Fused tail: one block per batch (512 threads = 8 waves).
__global__ __launch_bounds__(512) void radiomics_tail(
    const float* __restrict__ ws, float* __restrict__ out)
{
    __shared__ double fin[NQ];
    __shared__ double entp[NBINS];
    __shared__ double sh_hsum;
    const int b = blockIdx.x, tid = threadIdx.x;
    const int wave = tid >> 6, lane = tid & 63;

    for (int q = wave; q < NQ; q += 8) {
        const float* p = ws + ((size_t)b * NQ + q) * NSLOTS;
        double s = 0.0;
#pragma unroll
        for (int k = 0; k < 5; ++k) {
            int idx = lane + 64 * k;
            if (idx < NSLOTS) s += (double)p[idx];
        }
#pragma unroll
        for (int o = 32; o > 0; o >>= 1)
            s += __shfl_down(s, o, 64);
        if (lane == 0) fin[q] = s;
    }
    __syncthreads();

    if (tid == 0) {
        double h = 0.0;
        for (int k = 0; k < NBINS; ++k) h += fin[28 + k];
        sh_hsum = h + 1e-8;
    }
    __syncthreads();

    if (tid < NBINS) {
        double p = fin[28 + tid] / sh_hsum;
        entp[tid] = -p * log(p + 1e-8);
    }
    __syncthreads();

    if (tid == 0) {
        const double n  = fin[0];
        const double nn = fmax(n, 1.0);
        const double s1 = fin[1], s2 = fin[2], s3 = fin[3], s4 = fin[4];
        const double mu = s1 / nn;
        const double M2 = s2 - 2.0 * mu * s1 + mu * mu * n;
        const double M3 = s3 - 3.0 * mu * s2 + 3.0 * mu * mu * s1 - mu * mu * mu * n;
        const double M4 = s4 - 4.0 * mu * s3 + 6.0 * mu * mu * s2
                          - 4.0 * mu * mu * mu * s1 + mu * mu * mu * mu * n;
        const double var   = M2 / fmax(n - 1.0, 1.0);
        const double sigma = sqrt(var) + 1e-8;
        const double skew  = M3 / (sigma * sigma * sigma) / nn;
        const double kurt  = M4 / (sigma * sigma * sigma * sigma) / nn - 3.0;

        double ent = 0.0;
        for (int k = 0; k < NBINS; ++k) ent += entp[k];

        const double valid = (n >= 10.0) ? 1.0 : 0.0;
        float* ob = out + b * 25;
        ob[0] = (float)(mu * valid);
        ob[1] = (float)(sigma * valid);
        ob[2] = (float)(skew * valid);
        ob[3] = (float)(kurt * valid);
        ob[4] = (float)(ent * valid);

        const double lung = fmax(n, 1.0);
        for (int f = 0; f < 8; ++f) ob[5 + f]  = (float)(fin[5 + f] / lung);
        for (int f = 0; f < 6; ++f) ob[13 + f] = (float)(fin[13 + f] / lung);

        for (int ax = 0; ax < 3; ++ax) {
            double s  = fin[19 + ax];
            double ss = fmax(s, 1.0);
            double ok = (s >= 4.0) ? 1.0 : 0.0;
            ob[19 + 2 * ax]     = (float)(fin[22 + ax] / ss * ok);
            ob[19 + 2 * ax + 1] = (float)(fin[25 + ax] / ss * ok);
        }
    }
}

extern "C" void kernel_launch(void* const* d_in, const int* in_sizes, int n_in,
                              void* d_out, int out_size, void* d_ws, size_t ws_size,
                              hipStream_t stream)
{
    const float* x    = (const float*)d_in[0];
    const float* mask = (const float*)d_in[1];
    const float* gf   = (const float*)d_in[2];
    const float* lf   = (const float*)d_in[3];
    float* out = (float*)d_out;
    float* ws  = (float*)d_ws;    // 4*78*300 floats = 374.4 KB, fully overwritten

    dim3 grid(NTILE, NCHUNK, B_);   // 1200 blocks
    radiomics_main<<<grid, 256, 0, stream>>>(x, mask, gf, lf, ws);
    radiomics_tail<<<B_, 512, 0, stream>>>(ws, out);
}